// Round 17
// baseline (189.191 us; speedup 1.0000x reference)
//
#include <hip/hip_runtime.h>
#include <cstdint>
#include <cstddef>

typedef int int4v __attribute__((ext_vector_type(4)));
typedef signed char schar;

#define DEVI __device__ __forceinline__

DEVI void load_lds16(const void* g, void* l) {
  __builtin_amdgcn_global_load_lds(
      (const __attribute__((address_space(1))) void*)g,
      (__attribute__((address_space(3))) void*)l, 16, 0, 0);
}

// Bare advisory waits — no sched_barrier, no memory clobber.
#define BAR() __builtin_amdgcn_s_barrier()
#define LGKM(n) asm volatile("s_waitcnt lgkmcnt(" #n ")")
#define VMW(n) asm volatile("s_waitcnt vmcnt(" #n ")")

// ---- pack int32 -> int8, linear (4 elems/thread) ----
__global__ __launch_bounds__(256) void pack_i8(const int* __restrict__ src,
                                               signed char* __restrict__ dst,
                                               int n4) {
  int i = blockIdx.x * 256 + threadIdx.x;
  if (i >= n4) return;
  int4v v = ((const int4v*)src)[i];
  int p = (v.x & 255) | ((v.y & 255) << 8) | ((v.z & 255) << 16) | (v.w << 24);
  ((int*)dst)[i] = p;
}

// ---- pack + transpose: w[K][N] int32 -> wT[N][K] int8, 64x64 LDS tiles ----
__global__ __launch_bounds__(256) void pack_wT(const int* __restrict__ w,
                                               signed char* __restrict__ wT,
                                               int K, int N) {
  __shared__ signed char t[64][68];
  int n0 = blockIdx.x * 64, k0 = blockIdx.y * 64;
  int tr = threadIdx.x >> 6, tc = threadIdx.x & 63;
#pragma unroll
  for (int i = 0; i < 16; ++i) {
    int r = i * 4 + tr;
    t[r][tc] = (signed char)w[(size_t)(k0 + r) * N + n0 + tc];
  }
  __syncthreads();
#pragma unroll
  for (int i = 0; i < 16; ++i) {
    int r = i * 4 + tr;
    wT[(size_t)(n0 + r) * K + k0 + tc] = t[tc][r];
  }
}

// ---- 128x256-tile i8 GEMM, TWO INDEPENDENT BLOCKS PER CU ----
// 512 threads = 8 waves (2Mx4N), wave-tile 64x64, acc[4][4]=64 AGPR,
// ~120 regs (launch_bounds(512,4) caps at 128) -> 4 waves/SIMD ->
// TWO co-resident blocks/CU (LDS 48 KB each, 96 KB/CU).
// The R2-R16 plateau (14 schedule variants, all 87-96 us) was a convoy:
// ALL waves of the CU shared one barrier domain, so read bursts and MFMA
// bursts stayed phase-locked (per-tile time = serial sum, m114 says
// independent waves DO overlap MFMA and memory fully). Two blocks have
// unsynchronized barriers -> block A's MFMA covers block B's reads.
// BK=64 B (one 16x16x64 K-step), 2 buffers x 24 KB (A 8K + B 16K).
// Extra A-panel restaging (2x) is absorbed by L2/L3 (74 MB HBM FETCH
// today proves the caches carry staging refetch).
template <int EPI>
__global__ __launch_bounds__(512, 4) void gemmI(
    const schar* __restrict__ A, const schar* __restrict__ BT,
    int M, int N, int K, const int* __restrict__ bias_i,
    const float* __restrict__ alphaP, const float* __restrict__ betaP,
    const float* __restrict__ bias_f, schar* __restrict__ outQ,
    float* __restrict__ outF) {
  extern __shared__ schar lds[];

  const int tid = threadIdx.x;
  const int wid = tid >> 6, lane = tid & 63;
  const int wr = wid >> 2, wc = wid & 3;  // 2M x 4N waves, 64x64 each
  const int l16 = lane & 15, l4 = lane >> 4;

  // XCD-bijective block swizzle (nwg % 8 == 0 for both GEMMs)
  const int gx = gridDim.x;
  const int nwg = gx * gridDim.y;
  const int bid = blockIdx.y * gx + blockIdx.x;
  const int swz = (bid & 7) * (nwg >> 3) + (bid >> 3);
  const int rowBase = (swz / gx) * 128;   // 128 A-rows per tile
  const int colBase = (swz % gx) * 256;   // 256 B-cols per tile
  const int NT = K >> 6;  // 64-B K-tiles (16 or 64)

  const float alpha = alphaP[0];
  const float beta = (EPI == 0) ? betaP[0] : 0.f;
  asm volatile("" ::"s"(alpha), "s"(beta));
  LGKM(0);

  // staging sources (pre-swizzled 4-slot source; LDS dest linear).
  // A: 8 KB, one instr (o = tid*16). B: 16 KB, two chunks.
  const int oA = tid * 16;
  const int rA = oA >> 6;  // 0..127
  const int gA_ = ((oA >> 4) & 3) ^ ((rA >> 1) & 3);
  const schar* gAs = A + (size_t)(rowBase + rA) * K + gA_ * 16;
  const schar* gBs[2];
#pragma unroll
  for (int c = 0; c < 2; ++c) {
    int o = c * 8192 + tid * 16;
    int r = o >> 6;  // 0..255
    int g = ((o >> 4) & 3) ^ ((r >> 1) & 3);
    gBs[c] = BT + (size_t)(colBase + r) * K + g * 16;
  }

  auto stage = [&](int buf, int t) {
    schar* d = lds + buf * 24576 + wid * 1024;
    load_lds16(gAs + (size_t)t * 64, d);                     // A 8 KB
    load_lds16(gBs[0] + (size_t)t * 64, d + 8192);           // B half 0
    load_lds16(gBs[1] + (size_t)t * 64, d + 16384);          // B half 1
  };

  // fragment reads: slot = l4 ^ ((l16>>1)&3) (row bases mult of 16)
  const int slotc = (l4 ^ ((l16 >> 1) & 3)) * 16 + l16 * 64;
  const int aoff = wr * 4096 + slotc;          // + mi*1024
  const int boff = 8192 + wc * 4096 + slotc;   // + ni*1024

  int4v acc[4][4] = {};
  int4v aF[4], bF[4];

#define RDT(Bu)                                                    \
  do {                                                             \
    _Pragma("unroll") for (int mi = 0; mi < 4; ++mi) aF[mi] =      \
        *(const int4v*)((Bu) + aoff + mi * 1024);                  \
    _Pragma("unroll") for (int ni = 0; ni < 4; ++ni) bF[ni] =      \
        *(const int4v*)((Bu) + boff + ni * 1024);                  \
  } while (0)
#define MMT()                                                          \
  _Pragma("unroll") for (int mi = 0; mi < 4; ++mi)                     \
      _Pragma("unroll") for (int ni = 0; ni < 4; ++ni) acc[mi][ni] =   \
      __builtin_amdgcn_mfma_i32_16x16x64_i8(aF[mi], bF[ni],            \
                                            acc[mi][ni], 0, 0, 0)

  // prologue
  stage(0, 0);
  VMW(0);
  BAR();

  for (int T = 0; T < NT; ++T) {
    const schar* Bu = lds + (T & 1) * 24576;

    if (T + 1 < NT) stage((T + 1) & 1, T + 1);  // issue early

    RDT(Bu);
    MMT();  // compiler-counted lgkm waits; cross-BLOCK overlap de-convoys

    LGKM(0);  // own reads done (WAR vs next staging)
    VMW(0);   // own staging landed
    BAR();
  }

  // ---- epilogue; C/D frag: col = lane&15, row = (lane>>4)*4 + j ----
  if (EPI == 0) {
#pragma unroll
    for (int MI = 0; MI < 4; ++MI) {
      int row = rowBase + wr * 64 + MI * 16 + l4 * 4;
#pragma unroll
      for (int NI = 0; NI < 4; ++NI) {
        int col = colBase + wc * 64 + NI * 16 + l16;
        float bt = (float)bias_i[col] * beta;
#pragma unroll
        for (int j = 0; j < 4; ++j) {
          float h = (float)acc[MI][NI][j] * alpha + bt;
          h = fmaxf(h, 0.f);
          h = rintf(h);  // numpy round-half-even
          h = fminf(h, 127.f);
          outQ[(size_t)(row + j) * N + col] = (schar)h;
        }
      }
    }
  } else {
#pragma unroll
    for (int MI = 0; MI < 4; ++MI) {
      int row = rowBase + wr * 64 + MI * 16 + l4 * 4;
#pragma unroll
      for (int NI = 0; NI < 4; ++NI) {
        int col = colBase + wc * 64 + NI * 16 + l16;
        float bv = bias_f[col];
#pragma unroll
        for (int j = 0; j < 4; ++j)
          outF[(size_t)(row + j) * N + col] =
              (float)acc[MI][NI][j] * alpha + bv;
      }
    }
  }
#undef RDT
#undef MMT
}

extern "C" void kernel_launch(void* const* d_in, const int* in_sizes, int n_in,
                              void* d_out, int out_size, void* d_ws,
                              size_t ws_size, hipStream_t stream) {
  const int M = 16384, H = 1024, I = 4096;  // B*S = 16384
  const int* hidden = (const int*)d_in[0];
  const int* w_fc = (const int*)d_in[1];
  const int* b_fc = (const int*)d_in[2];
  const float* alpha_fc = (const float*)d_in[3];
  const float* beta_fc = (const float*)d_in[4];
  const int* w_proj = (const int*)d_in[5];
  const float* b_proj = (const float*)d_in[6];
  const float* alpha_proj = (const float*)d_in[7];
  float* out = (float*)d_out;

  signed char* hq = (signed char*)d_ws;     // [M][I]  64 MB
  signed char* aP = hq + (size_t)M * I;     // [M][H]  16 MB
  signed char* wfcT = aP + (size_t)M * H;   // [I][H]   4 MB (w_fc^T)
  signed char* wpT = wfcT + (size_t)I * H;  // [H][I]   4 MB (w_proj^T)

  pack_i8<<<(M * H / 4 + 255) / 256, 256, 0, stream>>>(hidden, aP, M * H / 4);
  pack_wT<<<dim3(I / 64, H / 64), 256, 0, stream>>>(w_fc, wfcT, H, I);
  pack_wT<<<dim3(H / 64, I / 64), 256, 0, stream>>>(w_proj, wpT, I, H);

  // tile 128(M) x 256(N); 48 KB dynamic LDS -> 2 blocks/CU
  gemmI<0><<<dim3(I / 256, M / 128), 512, 49152, stream>>>(
      aP, wfcT, M, I, H, b_fc, alpha_fc, beta_fc, nullptr, hq, nullptr);
  gemmI<1><<<dim3(H / 256, M / 128), 512, 49152, stream>>>(
      hq, wpT, M, H, I, nullptr, alpha_proj, nullptr, b_proj, nullptr, out);
}

// Round 18
// 182.456 us; speedup vs baseline: 1.0369x; 1.0369x over previous
//
#include <hip/hip_runtime.h>
#include <cstdint>
#include <cstddef>

typedef int int4v __attribute__((ext_vector_type(4)));
typedef signed char schar;

#define DEVI __device__ __forceinline__

DEVI void load_lds16(const void* g, void* l) {
  __builtin_amdgcn_global_load_lds(
      (const __attribute__((address_space(1))) void*)g,
      (__attribute__((address_space(3))) void*)l, 16, 0, 0);
}

// Bare advisory waits — no sched_barrier, no memory clobber.
#define BAR() __builtin_amdgcn_s_barrier()
#define LGKM(n) asm volatile("s_waitcnt lgkmcnt(" #n ")")
#define VMW(n) asm volatile("s_waitcnt vmcnt(" #n ")")

// ---- pack int32 -> int8, linear (4 elems/thread) ----
__global__ __launch_bounds__(256) void pack_i8(const int* __restrict__ src,
                                               signed char* __restrict__ dst,
                                               int n4) {
  int i = blockIdx.x * 256 + threadIdx.x;
  if (i >= n4) return;
  int4v v = ((const int4v*)src)[i];
  int p = (v.x & 255) | ((v.y & 255) << 8) | ((v.z & 255) << 16) | (v.w << 24);
  ((int*)dst)[i] = p;
}

// ---- pack + transpose: w[K][N] int32 -> wT[N][K] int8, 64x64 LDS tiles ----
__global__ __launch_bounds__(256) void pack_wT(const int* __restrict__ w,
                                               signed char* __restrict__ wT,
                                               int K, int N) {
  __shared__ signed char t[64][68];
  int n0 = blockIdx.x * 64, k0 = blockIdx.y * 64;
  int tr = threadIdx.x >> 6, tc = threadIdx.x & 63;
#pragma unroll
  for (int i = 0; i < 16; ++i) {
    int r = i * 4 + tr;
    t[r][tc] = (signed char)w[(size_t)(k0 + r) * N + n0 + tc];
  }
  __syncthreads();
#pragma unroll
  for (int i = 0; i < 16; ++i) {
    int r = i * 4 + tr;
    wT[(size_t)(n0 + r) * K + k0 + tc] = t[tc][r];
  }
}

// ---- 256x256 i8 GEMM + COHORT STAGGER: C = A[M,K] * BT[N,K]^T ----
// 8 waves (2Mx4N), 128x64 out/wave, acc[8][4]=128 AGPR, ~92 VGPR.
// BK=128 B (2 K-steps of 16x16x64), 2 LDS buffers (128 KiB).
// NEW vs R16: explicit time-symmetry breaking. The R2-R17 invariant
// (15 schedule variants, 87-96 us, MfmaUtil ~33%) is a shared-port
// convoy: fair round-robin LDS service means every wave's last operand
// returns at the END of the CU-wide drain, so all waves alternate
// read-burst / MFMA-burst in phase (even across independent blocks —
// R17 — because the shared port phase-locks them). Breaking it:
// the second wave of each SIMD (wid&4) sleeps ~1150 cy after issuing
// its staging; cohort A drains + MFMAs while cohort B sleeps; B then
// drains on the free port under A's MFMA; B MFMAs under staging.
// Per-tile target ~4200 cy vs measured 6600 serial sum.
template <int EPI>
__global__ __launch_bounds__(512, 2) void gemmS(
    const schar* __restrict__ A, const schar* __restrict__ BT,
    int M, int N, int K, const int* __restrict__ bias_i,
    const float* __restrict__ alphaP, const float* __restrict__ betaP,
    const float* __restrict__ bias_f, schar* __restrict__ outQ,
    float* __restrict__ outF) {
  extern __shared__ schar lds[];

  const int tid = threadIdx.x;
  const int wid = tid >> 6, lane = tid & 63;
  const int wr = wid >> 2, wc = wid & 3;  // 2M x 4N waves
  const int l16 = lane & 15, l4 = lane >> 4;
  const bool sleeper = (wid & 4) != 0;  // second wave of each SIMD

  // XCD-bijective block swizzle (nwg % 8 == 0 for both GEMMs)
  const int gx = gridDim.x;
  const int nwg = gx * gridDim.y;
  const int bid = blockIdx.y * gx + blockIdx.x;
  const int swz = (bid & 7) * (nwg >> 3) + (bid >> 3);
  const int rowBase = (swz / gx) * 256;
  const int colBase = (swz % gx) * 256;
  const int NT = K >> 7;

  const float alpha = alphaP[0];
  const float beta = (EPI == 0) ? betaP[0] : 0.f;
  asm volatile("" ::"s"(alpha), "s"(beta));
  LGKM(0);

  // staging source pointers (pre-swizzled global slot; LDS dest linear)
  const schar* gA[4];
  const schar* gB[4];
#pragma unroll
  for (int c = 0; c < 4; ++c) {
    int off = c * 8192 + tid * 16;
    int r = off >> 7;
    int gs = ((off >> 4) & 7) ^ (r & 7);
    gA[c] = A + (size_t)(rowBase + r) * K + gs * 16;
    gB[c] = BT + (size_t)(colBase + r) * K + gs * 16;
  }

  auto stage = [&](int buf, int t) {
#pragma unroll
    for (int c = 0; c < 4; ++c)
      load_lds16(gA[c] + (size_t)t * 128,
                 lds + buf * 32768 + c * 8192 + wid * 1024);
#pragma unroll
    for (int c = 0; c < 4; ++c)
      load_lds16(gB[c] + (size_t)t * 128,
                 lds + 65536 + buf * 32768 + c * 8192 + wid * 1024);
  };

  // fragment read offsets; row&7 == l16&7 so swizzle slot is lane-const
  const int so0 = ((0 + l4) ^ (l16 & 7)) * 16 + l16 * 128;  // kk=0
  const int so1 = ((4 + l4) ^ (l16 & 7)) * 16 + l16 * 128;  // kk=1

  int4v acc[8][4] = {};
  int4v aF[8], bF0[4], bF1[4];

#define RDA(SO, Ab)                                                  \
  _Pragma("unroll") for (int mi = 0; mi < 8; ++mi) aF[mi] =          \
      *(const int4v*)((Ab) + wr * 16384 + mi * 2048 + (SO))
#define RDB(DST, SO, Bb)                                             \
  _Pragma("unroll") for (int ni = 0; ni < 4; ++ni) (DST)[ni] =       \
      *(const int4v*)((Bb) + wc * 8192 + ni * 2048 + (SO))
#define MMALL(BF)                                                      \
  _Pragma("unroll") for (int mi = 0; mi < 8; ++mi)                     \
      _Pragma("unroll") for (int ni = 0; ni < 4; ++ni) acc[mi][ni] =   \
      __builtin_amdgcn_mfma_i32_16x16x64_i8(aF[mi], (BF)[ni],          \
                                            acc[mi][ni], 0, 0, 0)

  // prologue: stage tile 0, drain, barrier
  stage(0, 0);
  VMW(0);
  BAR();

  for (int T = 0; T < NT; ++T) {
    const int cb = T & 1, ob = cb ^ 1;
    const schar* Ab = lds + cb * 32768;
    const schar* Bb = lds + 65536 + cb * 32768;

    if (T + 1 < NT) stage(ob, T + 1);  // staging issued BEFORE the sleep

    // cohort stagger: second wave of each SIMD defers its read burst
    // (~18*64 = 1150 cy) so cohort A's drain+MFMA covers it and the
    // port serves each cohort while the other computes.
    if (sleeper) __builtin_amdgcn_s_sleep(18);

    RDB(bF0, so0, Bb);
    RDB(bF1, so1, Bb);
    RDA(so0, Ab);
    MMALL(bF0);  // compiler-counted lgkm waits interleave drain w/ issue
    RDA(so1, Ab);
    MMALL(bF1);

    LGKM(0);  // all reads of buffer cb done before leaving tile (WAR)
    VMW(0);   // own staging landed (issued a full tile earlier)
    BAR();    // publish buffer ob; re-seeds the stagger next tile
  }

  // ---- epilogue; C/D frag: col = lane&15, row = (lane>>4)*4 + j ----
  if (EPI == 0) {
#pragma unroll
    for (int MI = 0; MI < 8; ++MI) {
      int row = rowBase + wr * 128 + MI * 16 + l4 * 4;
#pragma unroll
      for (int NI = 0; NI < 4; ++NI) {
        int col = colBase + wc * 64 + NI * 16 + l16;
        float bt = (float)bias_i[col] * beta;
#pragma unroll
        for (int j = 0; j < 4; ++j) {
          float h = (float)acc[MI][NI][j] * alpha + bt;
          h = fmaxf(h, 0.f);
          h = rintf(h);  // numpy round-half-even
          h = fminf(h, 127.f);
          outQ[(size_t)(row + j) * N + col] = (schar)h;
        }
      }
    }
  } else {
#pragma unroll
    for (int MI = 0; MI < 8; ++MI) {
      int row = rowBase + wr * 128 + MI * 16 + l4 * 4;
#pragma unroll
      for (int NI = 0; NI < 4; ++NI) {
        int col = colBase + wc * 64 + NI * 16 + l16;
        float bv = bias_f[col];
#pragma unroll
        for (int j = 0; j < 4; ++j)
          outF[(size_t)(row + j) * N + col] =
              (float)acc[MI][NI][j] * alpha + bv;
      }
    }
  }
#undef RDA
#undef RDB
#undef MMALL
}

extern "C" void kernel_launch(void* const* d_in, const int* in_sizes, int n_in,
                              void* d_out, int out_size, void* d_ws,
                              size_t ws_size, hipStream_t stream) {
  const int M = 16384, H = 1024, I = 4096;  // B*S = 16384
  const int* hidden = (const int*)d_in[0];
  const int* w_fc = (const int*)d_in[1];
  const int* b_fc = (const int*)d_in[2];
  const float* alpha_fc = (const float*)d_in[3];
  const float* beta_fc = (const float*)d_in[4];
  const int* w_proj = (const int*)d_in[5];
  const float* b_proj = (const float*)d_in[6];
  const float* alpha_proj = (const float*)d_in[7];
  float* out = (float*)d_out;

  signed char* hq = (signed char*)d_ws;     // [M][I]  64 MB
  signed char* aP = hq + (size_t)M * I;     // [M][H]  16 MB
  signed char* wfcT = aP + (size_t)M * H;   // [I][H]   4 MB (w_fc^T)
  signed char* wpT = wfcT + (size_t)I * H;  // [H][I]   4 MB (w_proj^T)

  hipFuncSetAttribute((const void*)gemmS<0>,
                      hipFuncAttributeMaxDynamicSharedMemorySize, 131072);
  hipFuncSetAttribute((const void*)gemmS<1>,
                      hipFuncAttributeMaxDynamicSharedMemorySize, 131072);

  pack_i8<<<(M * H / 4 + 255) / 256, 256, 0, stream>>>(hidden, aP, M * H / 4);
  pack_wT<<<dim3(I / 64, H / 64), 256, 0, stream>>>(w_fc, wfcT, H, I);
  pack_wT<<<dim3(H / 64, I / 64), 256, 0, stream>>>(w_proj, wpT, I, H);

  gemmS<0><<<dim3(I / 256, M / 256), 512, 131072, stream>>>(
      aP, wfcT, M, I, H, b_fc, alpha_fc, beta_fc, nullptr, hq, nullptr);
  gemmS<1><<<dim3(H / 256, M / 256), 512, 131072, stream>>>(
      hq, wpT, M, H, I, nullptr, alpha_proj, nullptr, b_proj, nullptr, out);
}